// Round 1
// baseline (241.285 us; speedup 1.0000x reference)
//
#include <hip/hip_runtime.h>

// Problem constants (fixed by setup_inputs): B=128, C=3, N=320
constexpr int B    = 128;
constexpr int C    = 3;
constexpr int N    = 320;
constexpr int G    = N * N;        // 102400 elements per (b, c) plane
constexpr int G4   = G / 4;        // 25600 float4 chunks per plane
constexpr int ROW4 = N / 4;        // 80 float4 chunks per row
constexpr unsigned long long TOTAL_EDGES =
    (unsigned long long)B * (unsigned long long)(N * (N - 1) / 2); // 128*51040 = 6,533,120

__global__ __launch_bounds__(256) void edge_acc_kernel(
    const float* __restrict__ inp,   // [B, C, G] float32
    const int*   __restrict__ tgt,   // [B, G] int (harness passes integers as int32)
    unsigned int* __restrict__ counter)
{
    const int nChunks = B * G4;                       // 3,276,800
    const int tid     = blockIdx.x * blockDim.x + threadIdx.x;
    const int stride  = gridDim.x * blockDim.x;

    unsigned int cnt = 0;

    for (int cid = tid; cid < nChunks; cid += stride) {
        const int b  = cid / G4;
        const int q  = cid - b * G4;                  // chunk index within the plane
        const int i  = q / ROW4;                      // row in N x N
        const int jb = (q - i * ROW4) * 4;            // first column of this chunk

        // Strict upper triangle needs j > i. If even jb+3 <= i, the whole
        // chunk is masked -> skip all loads (halves HBM traffic).
        if (jb + 3 <= i) continue;

        const size_t plane = (size_t)b * C * G;
        const size_t gofs  = (size_t)q * 4;

        const float4 x0 = *(const float4*)(inp + plane            + gofs);
        const float4 x1 = *(const float4*)(inp + plane + (size_t)G     + gofs);
        const float4 x2 = *(const float4*)(inp + plane + (size_t)2 * G + gofs);
        const int4   tv = *(const int4*)(tgt + (size_t)b * G + gofs);

        // first-occurrence argmax over C=3 (matches jnp.argmax tie-breaking)
        {
            int pred = 0; float m = x0.x;
            if (x1.x > m) { m = x1.x; pred = 1; }
            if (x2.x > m) { pred = 2; }
            cnt += (unsigned)((jb + 0 > i) & (pred == tv.x));
        }
        {
            int pred = 0; float m = x0.y;
            if (x1.y > m) { m = x1.y; pred = 1; }
            if (x2.y > m) { pred = 2; }
            cnt += (unsigned)((jb + 1 > i) & (pred == tv.y));
        }
        {
            int pred = 0; float m = x0.z;
            if (x1.z > m) { m = x1.z; pred = 1; }
            if (x2.z > m) { pred = 2; }
            cnt += (unsigned)((jb + 2 > i) & (pred == tv.z));
        }
        {
            int pred = 0; float m = x0.w;
            if (x1.w > m) { m = x1.w; pred = 1; }
            if (x2.w > m) { pred = 2; }
            cnt += (unsigned)((jb + 3 > i) & (pred == tv.w));
        }
    }

    // ---- reduction: wave (64-lane shuffle) -> block (LDS) -> 1 atomic/block ----
    #pragma unroll
    for (int off = 32; off > 0; off >>= 1)
        cnt += __shfl_down(cnt, off, 64);

    __shared__ unsigned int wsum[4];                  // 256 threads = 4 waves
    const int lane = threadIdx.x & 63;
    const int wave = threadIdx.x >> 6;
    if (lane == 0) wsum[wave] = cnt;
    __syncthreads();

    if (threadIdx.x == 0) {
        unsigned int s = wsum[0] + wsum[1] + wsum[2] + wsum[3];
        if (s) atomicAdd(counter, s);
    }
}

__global__ void finalize_kernel(const unsigned int* __restrict__ counter,
                                float* __restrict__ out)
{
    const double acc = (double)counter[0] / (double)TOTAL_EDGES;
    out[0] = 1.0f - (float)acc;
}

extern "C" void kernel_launch(void* const* d_in, const int* in_sizes, int n_in,
                              void* d_out, int out_size, void* d_ws, size_t ws_size,
                              hipStream_t stream) {
    const float* inp = (const float*)d_in[0];
    const int*   tgt = (const int*)d_in[1];
    float*       out = (float*)d_out;
    unsigned int* counter = (unsigned int*)d_ws;

    // d_ws is re-poisoned to 0xAA before every launch -> zero the counter.
    hipMemsetAsync(counter, 0, sizeof(unsigned int), stream);

    const int threads = 256;
    const int blocks  = 2048;   // 8 blocks/CU, 8192 waves: plenty of TLP for HBM
    edge_acc_kernel<<<blocks, threads, 0, stream>>>(inp, tgt, counter);
    finalize_kernel<<<1, 1, 0, stream>>>(counter, out);
}

// Round 2
// 236.685 us; speedup vs baseline: 1.0194x; 1.0194x over previous
//
#include <hip/hip_runtime.h>

// Problem constants (fixed by setup_inputs): B=128, C=3, N=320
constexpr int B    = 128;
constexpr int C    = 3;
constexpr int N    = 320;
constexpr int G    = N * N;        // 102400 elements per (b, c) plane
constexpr int G4   = G / 4;        // 25600 float4 chunks per plane
constexpr int ROW4 = N / 4;        // 80 float4 chunks per row
constexpr int BLOCKS  = 3200;      // 3200*256 threads = 32 * G4 -> q invariant per thread
constexpr int THREADS = 256;
constexpr int BSTEP   = (BLOCKS * THREADS) / G4;  // 32 batches covered per sweep
constexpr int ITERS   = B / BSTEP;                // 4 iterations, exact
constexpr unsigned long long TOTAL_EDGES =
    (unsigned long long)B * (unsigned long long)(N * (N - 1) / 2); // 6,533,120

__global__ __launch_bounds__(THREADS) void edge_acc_kernel(
    const float* __restrict__ inp,      // [B, C, G] float32
    const int*   __restrict__ tgt,      // [B, G] int32
    unsigned int* __restrict__ partials) // [BLOCKS], plain stores (no init needed)
{
    const int tid = blockIdx.x * THREADS + threadIdx.x;   // 0 .. 819199
    const int q   = tid % G4;            // chunk within a plane (loop-invariant)
    const int b0  = tid / G4;            // 0 .. 31
    const int i   = q / ROW4;            // row in N x N
    const int jb  = (q - i * ROW4) * 4;  // first column of this chunk

    unsigned int cnt = 0;

    // Strict upper triangle: j > i. Whole-chunk skip decided ONCE per thread;
    // all 4 batch iterations share the same (i, jb).
    if (jb + 3 > i) {
        const unsigned m0 = (unsigned)(jb + 0 > i);
        const unsigned m1 = (unsigned)(jb + 1 > i);
        const unsigned m2 = (unsigned)(jb + 2 > i);
        const size_t gofs = (size_t)q * 4;

        #pragma unroll
        for (int it = 0; it < ITERS; ++it) {
            const int b = b0 + BSTEP * it;
            const float* p = inp + (size_t)b * (C * G) + gofs;

            const float4 x0 = *(const float4*)(p);
            const float4 x1 = *(const float4*)(p + G);
            const float4 x2 = *(const float4*)(p + 2 * G);
            const int4   tv = *(const int4*)(tgt + (size_t)b * G + gofs);

            // first-occurrence argmax over C=3 (matches jnp.argmax ties)
            {
                int pred = 0; float m = x0.x;
                if (x1.x > m) { m = x1.x; pred = 1; }
                if (x2.x > m) { pred = 2; }
                cnt += m0 & (unsigned)(pred == tv.x);
            }
            {
                int pred = 0; float m = x0.y;
                if (x1.y > m) { m = x1.y; pred = 1; }
                if (x2.y > m) { pred = 2; }
                cnt += m1 & (unsigned)(pred == tv.y);
            }
            {
                int pred = 0; float m = x0.z;
                if (x1.z > m) { m = x1.z; pred = 1; }
                if (x2.z > m) { pred = 2; }
                cnt += m2 & (unsigned)(pred == tv.z);
            }
            {
                int pred = 0; float m = x0.w;
                if (x1.w > m) { m = x1.w; pred = 1; }
                if (x2.w > m) { pred = 2; }
                cnt += (unsigned)(pred == tv.w);   // jb+3 > i guaranteed here
            }
        }
    }

    // ---- wave (64-lane shuffle) -> block (LDS) -> one plain store per block ----
    #pragma unroll
    for (int off = 32; off > 0; off >>= 1)
        cnt += __shfl_down(cnt, off, 64);

    __shared__ unsigned int wsum[THREADS / 64];
    const int lane = threadIdx.x & 63;
    const int wave = threadIdx.x >> 6;
    if (lane == 0) wsum[wave] = cnt;
    __syncthreads();

    if (threadIdx.x == 0)
        partials[blockIdx.x] = wsum[0] + wsum[1] + wsum[2] + wsum[3];
}

__global__ __launch_bounds__(256) void finalize_kernel(
    const unsigned int* __restrict__ partials,
    float* __restrict__ out)
{
    unsigned int s = 0;
    for (int idx = threadIdx.x; idx < BLOCKS; idx += 256)
        s += partials[idx];

    #pragma unroll
    for (int off = 32; off > 0; off >>= 1)
        s += __shfl_down(s, off, 64);

    __shared__ unsigned int wsum[4];
    const int lane = threadIdx.x & 63;
    const int wave = threadIdx.x >> 6;
    if (lane == 0) wsum[wave] = s;
    __syncthreads();

    if (threadIdx.x == 0) {
        const unsigned int total = wsum[0] + wsum[1] + wsum[2] + wsum[3];
        out[0] = 1.0f - (float)((double)total / (double)TOTAL_EDGES);
    }
}

extern "C" void kernel_launch(void* const* d_in, const int* in_sizes, int n_in,
                              void* d_out, int out_size, void* d_ws, size_t ws_size,
                              hipStream_t stream) {
    const float* inp = (const float*)d_in[0];
    const int*   tgt = (const int*)d_in[1];
    float*       out = (float*)d_out;
    unsigned int* partials = (unsigned int*)d_ws;  // BLOCKS * 4 bytes used

    edge_acc_kernel<<<BLOCKS, THREADS, 0, stream>>>(inp, tgt, partials);
    finalize_kernel<<<1, 256, 0, stream>>>(partials, out);
}

// Round 3
// 234.571 us; speedup vs baseline: 1.0286x; 1.0090x over previous
//
#include <hip/hip_runtime.h>

// Problem constants (fixed by setup_inputs): B=128, C=3, N=320
constexpr int B    = 128;
constexpr int C    = 3;
constexpr int N    = 320;
constexpr int G    = N * N;        // 102400 elements per (b, c) plane
constexpr int G4   = G / 4;        // 25600 float4 chunks per plane
constexpr int ROW4 = N / 4;        // 80 float4 chunks per row
constexpr int BLOCKS  = 1600;      // 1600*256 = 409600 = 16 * G4 -> q invariant per thread
constexpr int THREADS = 256;
constexpr int BSTEP   = (BLOCKS * THREADS) / G4;  // 16 batches covered per sweep
constexpr int ITERS   = B / BSTEP;                // 8 iterations, exact
constexpr unsigned long long TOTAL_EDGES =
    (unsigned long long)B * (unsigned long long)(N * (N - 1) / 2); // 6,533,120

__global__ __launch_bounds__(THREADS) void edge_acc_kernel(
    const float* __restrict__ inp,      // [B, C, G] float32
    const int*   __restrict__ tgt,      // [B, G] int32
    unsigned int* __restrict__ partials) // [BLOCKS], plain stores (no init needed)
{
    const int tid = blockIdx.x * THREADS + threadIdx.x;   // 0 .. 409599
    const int q   = tid % G4;            // chunk within a plane (loop-invariant)
    const int b0  = tid / G4;            // 0 .. 15
    const int i   = q / ROW4;            // row in N x N
    const int jb  = (q - i * ROW4) * 4;  // first column of this chunk

    unsigned int cnt = 0;

    // Strict upper triangle: j > i. Whole-chunk skip decided ONCE per thread;
    // all 8 batch iterations share the same (i, jb) -> 32 independent loads
    // in flight for active threads (MLP for HBM latency hiding).
    if (jb + 3 > i) {
        const unsigned m0 = (unsigned)(jb + 0 > i);
        const unsigned m1 = (unsigned)(jb + 1 > i);
        const unsigned m2 = (unsigned)(jb + 2 > i);
        const size_t gofs = (size_t)q * 4;

        #pragma unroll
        for (int it = 0; it < ITERS; ++it) {
            const int b = b0 + BSTEP * it;
            const float* p = inp + (size_t)b * (C * G) + gofs;

            const float4 x0 = *(const float4*)(p);
            const float4 x1 = *(const float4*)(p + G);
            const float4 x2 = *(const float4*)(p + 2 * G);
            const int4   tv = *(const int4*)(tgt + (size_t)b * G + gofs);

            // first-occurrence argmax over C=3 (matches jnp.argmax ties)
            {
                int pred = 0; float m = x0.x;
                if (x1.x > m) { m = x1.x; pred = 1; }
                if (x2.x > m) { pred = 2; }
                cnt += m0 & (unsigned)(pred == tv.x);
            }
            {
                int pred = 0; float m = x0.y;
                if (x1.y > m) { m = x1.y; pred = 1; }
                if (x2.y > m) { pred = 2; }
                cnt += m1 & (unsigned)(pred == tv.y);
            }
            {
                int pred = 0; float m = x0.z;
                if (x1.z > m) { m = x1.z; pred = 1; }
                if (x2.z > m) { pred = 2; }
                cnt += m2 & (unsigned)(pred == tv.z);
            }
            {
                int pred = 0; float m = x0.w;
                if (x1.w > m) { m = x1.w; pred = 1; }
                if (x2.w > m) { pred = 2; }
                cnt += (unsigned)(pred == tv.w);   // jb+3 > i guaranteed here
            }
        }
    }

    // ---- wave (64-lane shuffle) -> block (LDS) -> one plain store per block ----
    #pragma unroll
    for (int off = 32; off > 0; off >>= 1)
        cnt += __shfl_down(cnt, off, 64);

    __shared__ unsigned int wsum[THREADS / 64];
    const int lane = threadIdx.x & 63;
    const int wave = threadIdx.x >> 6;
    if (lane == 0) wsum[wave] = cnt;
    __syncthreads();

    if (threadIdx.x == 0)
        partials[blockIdx.x] = wsum[0] + wsum[1] + wsum[2] + wsum[3];
}

// Single-wave finalize: no LDS, no __syncthreads, int4 partial reads.
__global__ __launch_bounds__(64) void finalize_kernel(
    const unsigned int* __restrict__ partials,  // [BLOCKS], BLOCKS % 4 == 0
    float* __restrict__ out)
{
    unsigned int s = 0;
    const uint4* p4 = (const uint4*)partials;
    for (int idx = threadIdx.x; idx < BLOCKS / 4; idx += 64) {
        const uint4 v = p4[idx];
        s += v.x + v.y + v.z + v.w;
    }

    #pragma unroll
    for (int off = 32; off > 0; off >>= 1)
        s += __shfl_down(s, off, 64);

    if (threadIdx.x == 0)
        out[0] = 1.0f - (float)((double)s / (double)TOTAL_EDGES);
}

extern "C" void kernel_launch(void* const* d_in, const int* in_sizes, int n_in,
                              void* d_out, int out_size, void* d_ws, size_t ws_size,
                              hipStream_t stream) {
    const float* inp = (const float*)d_in[0];
    const int*   tgt = (const int*)d_in[1];
    float*       out = (float*)d_out;
    unsigned int* partials = (unsigned int*)d_ws;  // BLOCKS * 4 bytes used

    edge_acc_kernel<<<BLOCKS, THREADS, 0, stream>>>(inp, tgt, partials);
    finalize_kernel<<<1, 64, 0, stream>>>(partials, out);
}